// Round 1
// baseline (515.399 us; speedup 1.0000x reference)
//
#include <hip/hip_runtime.h>

typedef unsigned short u16;
typedef unsigned int u32;
typedef __attribute__((ext_vector_type(8))) short short8v;   // 8 bf16 (4 VGPRs)
typedef __attribute__((ext_vector_type(4))) float f32x4;

#define B 2
#define NF 5
#define C 256
#define HW 4096
#define CK 32
#define CV 128
#define NK 16384   // 4 frames * 4096
#define NQ 4096

__device__ __forceinline__ u16 f2bf(float f) {
    u32 u = __float_as_uint(f);
    u32 r = (u + 0x7FFFu + ((u >> 16) & 1u)) >> 16;   // RNE
    return (u16)r;
}

// ---------------- prep: transpose weights ----------------
__global__ __launch_bounds__(256) void prep_k(
    const float* __restrict__ qk_w, const float* __restrict__ mk_w,
    const float* __restrict__ qv_w, const float* __restrict__ mv_w,
    const float* __restrict__ sm_w,
    float* __restrict__ wkqT, float* __restrict__ wkmT,
    float* __restrict__ wvqT, float* __restrict__ wvmT,
    float* __restrict__ wsmT) {
    int idx = blockIdx.x * 256 + threadIdx.x;   // grid 256 -> 65536
    int o = idx >> 8, c = idx & 255;
    wsmT[c * 256 + o] = sm_w[idx];
    if (idx < 32 * 256)  { wkqT[c * 32 + o] = qk_w[idx]; wkmT[c * 32 + o] = mk_w[idx]; }
    if (idx < 128 * 256) { wvqT[c * 128 + o] = qv_w[idx]; wvmT[c * 128 + o] = mv_w[idx]; }
}

// ---------------- K projection + l2norm -> bf16 ----------------
__global__ __launch_bounds__(256) void proj_k(
    const float* __restrict__ x, const float* __restrict__ wkqT,
    const float* __restrict__ wkmT, u16* __restrict__ qkn, u16* __restrict__ mkn) {
    int bx = blockIdx.x;            // 2*5*16 = 160
    int bi = bx / 80;
    int rem = bx % 80;
    int f = rem / 16, pt = rem % 16;
    int p = pt * 256 + threadIdx.x;
    const float* W = (f == 4) ? wkqT : wkmT;
    const float* xp = x + (((size_t)bi * NF + f) * C) * HW + p;
    float acc[32];
#pragma unroll
    for (int i = 0; i < 32; i++) acc[i] = 0.f;
    for (int c = 0; c < 256; c++) {
        float xv = xp[(size_t)c * HW];
        const f32x4* w4 = (const f32x4*)(W + c * 32);
#pragma unroll
        for (int i = 0; i < 8; i++) {
            f32x4 w = w4[i];
#pragma unroll
            for (int j = 0; j < 4; j++) acc[4 * i + j] += w[j] * xv;
        }
    }
    float ss = 0.f;
#pragma unroll
    for (int i = 0; i < 32; i++) ss += acc[i] * acc[i];
    float rn = 1.0f / fmaxf(sqrtf(ss), 1e-12f);
    u16* dst = (f == 4) ? (qkn + ((size_t)bi * NQ + p) * 32)
                        : (mkn + ((size_t)bi * NK + f * HW + p) * 32);
#pragma unroll
    for (int j = 0; j < 4; j++) {
        short8v v;
#pragma unroll
        for (int e = 0; e < 8; e++) v[e] = (short)f2bf(acc[j * 8 + e] * rn);
        *(short8v*)(dst + j * 8) = v;
    }
}

// ---------------- V projection: qv f32 channel-major, mv bf16 channel-major ----------------
__global__ __launch_bounds__(256) void proj_v(
    const float* __restrict__ x, const float* __restrict__ wvqT,
    const float* __restrict__ wvmT, float* __restrict__ qv, u16* __restrict__ mvt) {
    int bx = blockIdx.x;            // 2*5*32 = 320
    int bi = bx / 160;
    int rem = bx % 160;
    int f = rem / 32, pt = rem % 32;
    int oh = threadIdx.x >> 7, pl = threadIdx.x & 127;   // oh wave-uniform
    int p = pt * 128 + pl;
    const float* W = (f == 4) ? wvqT : wvmT;
    const float* xp = x + (((size_t)bi * NF + f) * C) * HW + p;
    float acc[64];
#pragma unroll
    for (int i = 0; i < 64; i++) acc[i] = 0.f;
    for (int c = 0; c < 256; c++) {
        float xv = xp[(size_t)c * HW];
        const f32x4* w4 = (const f32x4*)(W + (size_t)c * 128 + oh * 64);
#pragma unroll
        for (int i = 0; i < 16; i++) {
            f32x4 w = w4[i];
#pragma unroll
            for (int j = 0; j < 4; j++) acc[4 * i + j] += w[j] * xv;
        }
    }
    if (f == 4) {
#pragma unroll
        for (int i = 0; i < 64; i++)
            qv[((size_t)bi * CV + oh * 64 + i) * HW + p] = acc[i];
    } else {
#pragma unroll
        for (int i = 0; i < 64; i++)
            mvt[((size_t)bi * CV + oh * 64 + i) * NK + f * HW + p] = f2bf(acc[i]);
    }
}

// ---------------- flash attention (fixed-shift softmax: scores in [-1,1]) ----------------
__global__ __launch_bounds__(512) void attn_k(
    const u16* __restrict__ qkn, const u16* __restrict__ mkn,
    const u16* __restrict__ mvt, float* __restrict__ opart,
    float* __restrict__ lpart, int kc) {
    __shared__ alignas(16) u16 klds[64 * 40];        // [64 keys][32c +8 pad]
    __shared__ alignas(16) u16 vt[128 * 72];         // [128 v][64 k +8 pad]
    __shared__ alignas(16) u16 plds[8 * 16 * 72];    // per-wave [16 q][64 k +8 pad]

    int bx = blockIdx.x;
    int bi = bx / (32 * kc);
    int rem = bx % (32 * kc);
    int qt = rem / kc;
    int kci = rem % kc;
    int chunk = NK / kc;
    int iters = chunk / 64;
    int tid = threadIdx.x;
    int wave = tid >> 6, lane = tid & 63;
    int l15 = lane & 15, cg = lane >> 4;

    // Q fragment (A-layout: row q = lane&15, c = cg*8+j), loaded once
    int qrow = qt * 128 + wave * 16 + l15;
    short8v qf = *(const short8v*)(qkn + ((size_t)bi * NQ + qrow) * 32 + cg * 8);

    f32x4 O[8];
#pragma unroll
    for (int n = 0; n < 8; n++) O[n] = (f32x4){0.f, 0.f, 0.f, 0.f};
    float lac[4] = {0.f, 0.f, 0.f, 0.f};

    const char* klc = (const char*)klds;
    const char* vtc = (const char*)vt;
    char* plc = (char*)plds;

    for (int it = 0; it < iters; ++it) {
        int k0 = kci * chunk + it * 64;
        __syncthreads();   // previous iter's LDS reads complete before overwrite
        if (tid < 256) {   // stage K: 64 keys x 64B
            int k = tid >> 2, co = (tid & 3) * 8;
            short8v kv = *(const short8v*)(mkn + ((size_t)bi * NK + k0 + k) * 32 + co);
            *(short8v*)((char*)klds + k * 80 + co * 2) = kv;
        }
#pragma unroll
        for (int rep = 0; rep < 2; rep++) {   // stage V: 128 rows x 128B
            int v = (tid >> 3) + rep * 64;
            int ko = (tid & 7) * 8;
            short8v vv = *(const short8v*)(mvt + ((size_t)bi * CV + v) * NK + k0 + ko);
            *(short8v*)((char*)vt + v * 144 + ko * 2) = vv;
        }
        __syncthreads();

        // S = Q·K^T  (4 k-subtiles of 16)
        f32x4 zero = (f32x4){0.f, 0.f, 0.f, 0.f};
        f32x4 sf[4];
#pragma unroll
        for (int s = 0; s < 4; s++) {
            short8v kf = *(const short8v*)(klc + (s * 16 + l15) * 80 + cg * 16);
            sf[s] = __builtin_amdgcn_mfma_f32_16x16x32_bf16(qf, kf, zero, 0, 0, 0);
        }
        // P = exp(s-1); accumulate own-column l; scatter P (D-layout) to LDS
        char* pb = plc + (wave * 16 + cg * 4) * 144 + l15 * 2;
#pragma unroll
        for (int s = 0; s < 4; s++) {
#pragma unroll
            for (int r = 0; r < 4; r++) {
                float pv = __expf(sf[s][r] - 1.0f);
                u16 ph = f2bf(pv);
                lac[r] += __uint_as_float(((u32)ph) << 16);   // l from rounded P
                *(u16*)(pb + r * 144 + s * 32) = ph;
            }
        }
        // O += P·V   (A-layout read of P from LDS)
#pragma unroll
        for (int s2 = 0; s2 < 2; s2++) {
            short8v af = *(const short8v*)(plc + (wave * 16 + l15) * 144 + s2 * 64 + cg * 16);
#pragma unroll
            for (int n = 0; n < 8; n++) {
                short8v vf = *(const short8v*)(vtc + (n * 16 + l15) * 144 + s2 * 64 + cg * 16);
                O[n] = __builtin_amdgcn_mfma_f32_16x16x32_bf16(af, vf, O[n], 0, 0, 0);
            }
        }
    }
    // reduce l across the 16-lane (k) groups
#pragma unroll
    for (int r = 0; r < 4; r++)
        for (int off = 1; off < 16; off <<= 1)
            lac[r] += __shfl_xor(lac[r], off, 64);

    size_t base = ((size_t)bi * kc + kci) * NQ;
#pragma unroll
    for (int n = 0; n < 8; n++) {
#pragma unroll
        for (int r = 0; r < 4; r++) {
            int q = qt * 128 + wave * 16 + cg * 4 + r;
            opart[(base + q) * 128 + n * 16 + l15] = O[n][r];
        }
    }
    if (l15 == 0) {
#pragma unroll
        for (int r = 0; r < 4; r++) {
            int q = qt * 128 + wave * 16 + cg * 4 + r;
            lpart[base + q] = lac[r];
        }
    }
}

// ---------------- split-K combine + transpose -> agg_t [b][128][4096] ----------------
__global__ __launch_bounds__(256) void combine_k(
    const float* __restrict__ opart, const float* __restrict__ lpart,
    float* __restrict__ aggt, int kc) {
    __shared__ float tr[128][65];
    int bx = blockIdx.x;            // 2*64 = 128
    int bi = bx >> 6;
    int qb = (bx & 63) * 64;
    int t = threadIdx.x;
    int v4 = (t & 31) * 4;
    for (int rep = 0; rep < 8; rep++) {
        int ql = (t >> 5) + rep * 8;
        int q = qb + ql;
        f32x4 s = (f32x4){0.f, 0.f, 0.f, 0.f};
        float lsum = 0.f;
        for (int k = 0; k < kc; k++) {
            size_t pb = ((size_t)bi * kc + k) * NQ + q;
            f32x4 o4 = *(const f32x4*)(opart + pb * 128 + v4);
            s += o4;
            lsum += lpart[pb];
        }
        float rcp = 1.0f / lsum;
        tr[v4 + 0][ql] = s[0] * rcp;
        tr[v4 + 1][ql] = s[1] * rcp;
        tr[v4 + 2][ql] = s[2] * rcp;
        tr[v4 + 3][ql] = s[3] * rcp;
    }
    __syncthreads();
    int v = t >> 1, qh = (t & 1) * 32;
    float* dst = aggt + ((size_t)bi * CV + v) * HW + qb + qh;
#pragma unroll
    for (int j = 0; j < 32; j++) dst[j] = tr[v][qh + j];
}

// ---------------- output GEMM (+BN+ReLU) ----------------
__global__ __launch_bounds__(256) void final_k(
    const float* __restrict__ qv, const float* __restrict__ aggt,
    const float* __restrict__ wsmT,
    const float* __restrict__ bns, const float* __restrict__ bnb,
    const float* __restrict__ bnm, const float* __restrict__ bnv,
    float* __restrict__ out) {
    int bx = blockIdx.x;            // 2*8*64 = 1024
    int bi = bx >> 9;
    int rem = bx & 511;
    int ot = rem >> 6, pt = rem & 63;
    int wave = threadIdx.x >> 6, lane = threadIdx.x & 63;
    int o0 = ot * 32 + wave * 8;    // wave-uniform
    int p = pt * 64 + lane;
    float acc[8] = {0.f, 0.f, 0.f, 0.f, 0.f, 0.f, 0.f, 0.f};
    const float* uq = qv + ((size_t)bi * CV) * HW + p;
    const float* ua = aggt + ((size_t)bi * CV) * HW + p;
    for (int c = 0; c < 256; c++) {
        float u = (c < 128) ? uq[(size_t)c * HW] : ua[(size_t)(c - 128) * HW];
        const f32x4* w4 = (const f32x4*)(wsmT + (size_t)c * 256 + o0);
        f32x4 wa = w4[0], wb = w4[1];
#pragma unroll
        for (int j = 0; j < 4; j++) { acc[j] += wa[j] * u; acc[4 + j] += wb[j] * u; }
    }
#pragma unroll
    for (int i = 0; i < 8; i++) {
        int o = o0 + i;
        float inv = bns[o] / sqrtf(bnv[o] + 1e-5f);
        float val = (acc[i] - bnm[o]) * inv + bnb[o];
        val = fmaxf(val, 0.f);
        out[(((size_t)bi * NF + 4) * C + o) * HW + p] = val;
    }
}

// ---------------- copy xm frames ----------------
__global__ __launch_bounds__(256) void copy_xm(const float* __restrict__ x, float* __restrict__ out) {
    int idx = blockIdx.x * 256 + threadIdx.x;   // 2 * 1048576 float4s
    int bi = idx >> 20;
    int i = idx & 1048575;
    size_t off = (size_t)bi * (NF * C * HW / 4) + i;
    ((f32x4*)out)[off] = ((const f32x4*)x)[off];
}

extern "C" void kernel_launch(void* const* d_in, const int* in_sizes, int n_in,
                              void* d_out, int out_size, void* d_ws, size_t ws_size,
                              hipStream_t stream) {
    const float* x    = (const float*)d_in[0];
    const float* qk_w = (const float*)d_in[2];
    const float* qv_w = (const float*)d_in[3];
    const float* mk_w = (const float*)d_in[4];
    const float* mv_w = (const float*)d_in[5];
    const float* sm_w = (const float*)d_in[6];
    const float* bns  = (const float*)d_in[7];
    const float* bnb  = (const float*)d_in[8];
    const float* bnm  = (const float*)d_in[9];
    const float* bnv  = (const float*)d_in[10];
    float* out = (float*)d_out;
    char* ws = (char*)d_ws;

    size_t off = 0;
    auto alloc = [&](size_t bytes) { size_t o = off; off += (bytes + 255) & ~(size_t)255; return o; };
    size_t WKQ = alloc(256 * 32 * 4),  WKM = alloc(256 * 32 * 4);
    size_t WVQ = alloc(256 * 128 * 4), WVM = alloc(256 * 128 * 4);
    size_t WSM = alloc(256 * 256 * 4);
    size_t QKN = alloc((size_t)B * NQ * 32 * 2);
    size_t MKN = alloc((size_t)B * NK * 32 * 2);
    size_t QV  = alloc((size_t)B * CV * HW * 4);
    size_t MVT = alloc((size_t)B * CV * NK * 2);
    size_t AGT = alloc((size_t)B * CV * HW * 4);
    size_t fixed = off;
    int kc = 4;
    size_t need4 = fixed + (size_t)B * 4 * NQ * 4 + (size_t)B * 4 * NQ * 128 * 4;
    if (ws_size < need4) kc = 1;   // fallback: fewer blocks, less scratch
    size_t LP = alloc((size_t)B * kc * NQ * 4);
    size_t OP = alloc((size_t)B * kc * NQ * 128 * 4);

    prep_k<<<256, 256, 0, stream>>>(qk_w, mk_w, qv_w, mv_w, sm_w,
        (float*)(ws + WKQ), (float*)(ws + WKM), (float*)(ws + WVQ),
        (float*)(ws + WVM), (float*)(ws + WSM));
    proj_k<<<160, 256, 0, stream>>>(x, (float*)(ws + WKQ), (float*)(ws + WKM),
        (u16*)(ws + QKN), (u16*)(ws + MKN));
    proj_v<<<320, 256, 0, stream>>>(x, (float*)(ws + WVQ), (float*)(ws + WVM),
        (float*)(ws + QV), (u16*)(ws + MVT));
    attn_k<<<B * 32 * kc, 512, 0, stream>>>((u16*)(ws + QKN), (u16*)(ws + MKN),
        (u16*)(ws + MVT), (float*)(ws + OP), (float*)(ws + LP), kc);
    combine_k<<<128, 256, 0, stream>>>((float*)(ws + OP), (float*)(ws + LP),
        (float*)(ws + AGT), kc);
    final_k<<<1024, 256, 0, stream>>>((float*)(ws + QV), (float*)(ws + AGT),
        (float*)(ws + WSM), bns, bnb, bnm, bnv, out);
    copy_xm<<<8192, 256, 0, stream>>>(x, out);
}

// Round 2
// 187.824 us; speedup vs baseline: 2.7441x; 2.7441x over previous
//
#include <hip/hip_runtime.h>

typedef unsigned short u16;
typedef unsigned int u32;
typedef __attribute__((ext_vector_type(8))) short short8v;   // 8 bf16 (4 VGPRs)
typedef __attribute__((ext_vector_type(4))) float f32x4;

#define B 2
#define NF 5
#define C 256
#define HW 4096
#define CV 128
#define NK 16384   // 4 frames * 4096
#define NQ 4096

__device__ __forceinline__ u16 f2bf(float f) {
    u32 u = __float_as_uint(f);
    u32 r = (u + 0x7FFFu + ((u >> 16) & 1u)) >> 16;   // RNE
    return (u16)r;
}

// ---------------- prep: bf16 weight tables + BN folding ----------------
// wb[2][160][256] bf16: v=0 -> {mk_w(32) ; mv_w(128)}, v=1 -> {qk_w ; qv_w}
// wsf[256][256] bf16 = sm_w * inv[o];  bias2[o] = bnb - bnm*inv
__global__ __launch_bounds__(256) void prep_k(
    const float* __restrict__ qk_w, const float* __restrict__ qv_w,
    const float* __restrict__ mk_w, const float* __restrict__ mv_w,
    const float* __restrict__ sm_w,
    const float* __restrict__ bns, const float* __restrict__ bnb,
    const float* __restrict__ bnm, const float* __restrict__ bnv,
    u16* __restrict__ wsf, float* __restrict__ bias2, u16* __restrict__ wb) {
    int bx = blockIdx.x, t = threadIdx.x;
    if (bx < 256) {
        int idx = bx * 256 + t;          // o*256 + c
        int o = idx >> 8;
        float inv = bns[o] / sqrtf(bnv[o] + 1e-5f);
        wsf[idx] = f2bf(sm_w[idx] * inv);
    } else if (bx < 576) {
        int j = (bx - 256) * 256 + t;    // < 81920
        int v = j / 40960, rr = j % 40960;
        int row = rr >> 8, c = rr & 255;
        float s;
        if (v == 0) s = (row < 32) ? mk_w[row * 256 + c] : mv_w[(row - 32) * 256 + c];
        else        s = (row < 32) ? qk_w[row * 256 + c] : qv_w[(row - 32) * 256 + c];
        wb[j] = f2bf(s);
    } else {
        int o = t;
        float inv = bns[o] / sqrtf(bnv[o] + 1e-5f);
        bias2[o] = bnb[o] - bnm[o] * inv;
    }
}

// ---------------- fused K+V projection via MFMA ----------------
// Per (b,f,ptile of 64): D[o=160][p=64] = W[160][256] x X[p][256]^T
// A-frag: wb rows (o, c contiguous).  B-frag: 8 strided x loads + bf16 pack.
__global__ __launch_bounds__(256) void proj_mfma(
    const float* __restrict__ x, const u16* __restrict__ wb,
    u16* __restrict__ qkn, u16* __restrict__ mkn,
    u16* __restrict__ mvt, u16* __restrict__ U) {
    int bx = blockIdx.x;        // 2*5*64 = 640
    int bi = bx / 320;
    int rem = bx % 320;
    int f = rem >> 6, pt = rem & 63;
    int t = threadIdx.x, w = t >> 6, lane = t & 63;
    int l15 = lane & 15, cg = lane >> 4;
    int p = pt * 64 + w * 16 + l15;
    const float* xp = x + (((size_t)bi * NF + f) * C) * HW + p;
    const u16* wrow = wb + (size_t)((f == 4) ? 160 : 0) * 256;

    f32x4 acc[10];
#pragma unroll
    for (int m = 0; m < 10; m++) acc[m] = (f32x4){0.f, 0.f, 0.f, 0.f};

    for (int k = 0; k < 8; k++) {
        float xv[8];
#pragma unroll
        for (int j = 0; j < 8; j++) xv[j] = xp[(size_t)(k * 32 + cg * 8 + j) * HW];
        short8v bfrag;
#pragma unroll
        for (int j = 0; j < 8; j++) bfrag[j] = (short)f2bf(xv[j]);
#pragma unroll
        for (int m = 0; m < 10; m++) {
            short8v afrag = *(const short8v*)(wrow + (size_t)(m * 16 + l15) * 256 + k * 32 + cg * 8);
            acc[m] = __builtin_amdgcn_mfma_f32_16x16x32_bf16(afrag, bfrag, acc[m], 0, 0, 0);
        }
    }

    // l2-norm over the 32 K channels (m-tiles 0,1); D col = l15 = pixel
    float ssq = 0.f;
#pragma unroll
    for (int m = 0; m < 2; m++)
#pragma unroll
        for (int r = 0; r < 4; r++) ssq += acc[m][r] * acc[m][r];
    ssq += __shfl_xor(ssq, 16, 64);
    ssq += __shfl_xor(ssq, 32, 64);
    float rn = 1.0f / fmaxf(sqrtf(ssq), 1e-12f);

    if (f == 4) {
        u16* kd = qkn + ((size_t)bi * NQ + p) * 32;
#pragma unroll
        for (int m = 0; m < 2; m++)
#pragma unroll
            for (int r = 0; r < 4; r++) kd[m * 16 + cg * 4 + r] = f2bf(acc[m][r] * rn);
        // query_v -> U[b][p][0..127] bf16 (8B packed stores)
        u16* ud = U + ((size_t)bi * HW + p) * 256;
#pragma unroll
        for (int m = 2; m < 10; m++) {
            int vo = m * 16 - 32 + cg * 4;
            union { u16 h[4]; uint2 v; } pk;
#pragma unroll
            for (int r = 0; r < 4; r++) pk.h[r] = f2bf(acc[m][r]);
            *(uint2*)(ud + vo) = pk.v;
        }
    } else {
        u16* kd = mkn + ((size_t)bi * NK + f * HW + p) * 32;
#pragma unroll
        for (int m = 0; m < 2; m++)
#pragma unroll
            for (int r = 0; r < 4; r++) kd[m * 16 + cg * 4 + r] = f2bf(acc[m][r] * rn);
#pragma unroll
        for (int m = 2; m < 10; m++)
#pragma unroll
            for (int r = 0; r < 4; r++) {
                int vo = m * 16 - 32 + cg * 4 + r;
                mvt[((size_t)bi * CV + vo) * NK + f * HW + p] = f2bf(acc[m][r]);
            }
    }
}

// ---------------- flash attention (fixed-shift softmax: scores in [-1,1]) ----------------
__global__ __launch_bounds__(512) void attn_k(
    const u16* __restrict__ qkn, const u16* __restrict__ mkn,
    const u16* __restrict__ mvt, float* __restrict__ opart,
    float* __restrict__ lpart, int kc) {
    __shared__ alignas(16) u16 klds[64 * 40];        // [64 keys][32c +8 pad]
    __shared__ alignas(16) u16 vt[128 * 72];         // [128 v][64 k +8 pad]
    __shared__ alignas(16) u16 plds[8 * 16 * 72];    // per-wave [16 q][64 k +8 pad]

    int bx = blockIdx.x;
    int bi = bx / (32 * kc);
    int rem = bx % (32 * kc);
    int qt = rem / kc;
    int kci = rem % kc;
    int chunk = NK / kc;
    int iters = chunk / 64;
    int tid = threadIdx.x;
    int wave = tid >> 6, lane = tid & 63;
    int l15 = lane & 15, cg = lane >> 4;

    int qrow = qt * 128 + wave * 16 + l15;
    short8v qf = *(const short8v*)(qkn + ((size_t)bi * NQ + qrow) * 32 + cg * 8);

    f32x4 O[8];
#pragma unroll
    for (int n = 0; n < 8; n++) O[n] = (f32x4){0.f, 0.f, 0.f, 0.f};
    float lac[4] = {0.f, 0.f, 0.f, 0.f};

    const char* klc = (const char*)klds;
    const char* vtc = (const char*)vt;
    char* plc = (char*)plds;

    for (int it = 0; it < iters; ++it) {
        int k0 = kci * chunk + it * 64;
        __syncthreads();
        if (tid < 256) {   // stage K: 64 keys x 64B
            int k = tid >> 2, co = (tid & 3) * 8;
            short8v kv = *(const short8v*)(mkn + ((size_t)bi * NK + k0 + k) * 32 + co);
            *(short8v*)((char*)klds + k * 80 + co * 2) = kv;
        }
#pragma unroll
        for (int rep = 0; rep < 2; rep++) {   // stage V: 128 rows x 128B
            int v = (tid >> 3) + rep * 64;
            int ko = (tid & 7) * 8;
            short8v vv = *(const short8v*)(mvt + ((size_t)bi * CV + v) * NK + k0 + ko);
            *(short8v*)((char*)vt + v * 144 + ko * 2) = vv;
        }
        __syncthreads();

        f32x4 zero = (f32x4){0.f, 0.f, 0.f, 0.f};
        f32x4 sf[4];
#pragma unroll
        for (int s = 0; s < 4; s++) {
            short8v kf = *(const short8v*)(klc + (s * 16 + l15) * 80 + cg * 16);
            sf[s] = __builtin_amdgcn_mfma_f32_16x16x32_bf16(qf, kf, zero, 0, 0, 0);
        }
        char* pb = plc + (wave * 16 + cg * 4) * 144 + l15 * 2;
#pragma unroll
        for (int s = 0; s < 4; s++) {
#pragma unroll
            for (int r = 0; r < 4; r++) {
                float pv = __expf(sf[s][r] - 1.0f);
                u16 ph = f2bf(pv);
                lac[r] += __uint_as_float(((u32)ph) << 16);
                *(u16*)(pb + r * 144 + s * 32) = ph;
            }
        }
#pragma unroll
        for (int s2 = 0; s2 < 2; s2++) {
            short8v af = *(const short8v*)(plc + (wave * 16 + l15) * 144 + s2 * 64 + cg * 16);
#pragma unroll
            for (int n = 0; n < 8; n++) {
                short8v vf = *(const short8v*)(vtc + (n * 16 + l15) * 144 + s2 * 64 + cg * 16);
                O[n] = __builtin_amdgcn_mfma_f32_16x16x32_bf16(af, vf, O[n], 0, 0, 0);
            }
        }
    }
#pragma unroll
    for (int r = 0; r < 4; r++)
        for (int off = 1; off < 16; off <<= 1)
            lac[r] += __shfl_xor(lac[r], off, 64);

    size_t base = ((size_t)bi * kc + kci) * NQ;
#pragma unroll
    for (int n = 0; n < 8; n++) {
#pragma unroll
        for (int r = 0; r < 4; r++) {
            int q = qt * 128 + wave * 16 + cg * 4 + r;
            opart[(base + q) * 128 + n * 16 + l15] = O[n][r];
        }
    }
    if (l15 == 0) {
#pragma unroll
        for (int r = 0; r < 4; r++) {
            int q = qt * 128 + wave * 16 + cg * 4 + r;
            lpart[base + q] = lac[r];
        }
    }
}

// ---------------- split-K combine -> U[b][q][128..255] bf16 ----------------
__global__ __launch_bounds__(256) void combine_k(
    const float* __restrict__ opart, const float* __restrict__ lpart,
    u16* __restrict__ U, int kc) {
    int bx = blockIdx.x;            // B * 128 = 256
    int bi = bx >> 7;
    int qt = bx & 127;
    int t = threadIdx.x;
    int ql = t >> 3, vs = (t & 7) * 16;
    int q = qt * 32 + ql;
    f32x4 s[4];
#pragma unroll
    for (int i = 0; i < 4; i++) s[i] = (f32x4){0.f, 0.f, 0.f, 0.f};
    float lsum = 0.f;
    for (int k = 0; k < kc; k++) {
        size_t pb = ((size_t)bi * kc + k) * NQ + q;
        const f32x4* op4 = (const f32x4*)(opart + pb * 128 + vs);
#pragma unroll
        for (int i = 0; i < 4; i++) s[i] += op4[i];
        lsum += lpart[pb];
    }
    float rcp = 1.0f / lsum;
    u16* ud = U + ((size_t)bi * HW + q) * 256 + 128 + vs;
    union { u16 h[8]; short8v v; } pk0, pk1;
#pragma unroll
    for (int e = 0; e < 8; e++) pk0.h[e] = f2bf(s[e >> 2][e & 3] * rcp);
#pragma unroll
    for (int e = 0; e < 8; e++) pk1.h[e] = f2bf(s[2 + (e >> 2)][e & 3] * rcp);
    *(short8v*)ud = pk0.v;
    *(short8v*)(ud + 8) = pk1.v;
}

// ---------------- output GEMM via MFMA (+folded BN+ReLU) ----------------
__global__ __launch_bounds__(256) void final_mfma(
    const u16* __restrict__ U, const u16* __restrict__ wsf,
    const float* __restrict__ bias2, float* __restrict__ out) {
    int bx = blockIdx.x;          // 2*2*64 = 256
    int bi = bx >> 7;
    int mh = (bx >> 6) & 1;
    int pt = bx & 63;
    int t = threadIdx.x, w = t >> 6, lane = t & 63;
    int l15 = lane & 15, cg = lane >> 4;
    int p = pt * 64 + w * 16 + l15;
    const u16* urow = U + ((size_t)bi * HW + p) * 256;
    const u16* wbase = wsf + (size_t)mh * 128 * 256;
    f32x4 acc[8];
#pragma unroll
    for (int m = 0; m < 8; m++) acc[m] = (f32x4){0.f, 0.f, 0.f, 0.f};
    for (int k = 0; k < 8; k++) {
        short8v bfrag = *(const short8v*)(urow + k * 32 + cg * 8);
#pragma unroll
        for (int m = 0; m < 8; m++) {
            short8v afrag = *(const short8v*)(wbase + (size_t)(m * 16 + l15) * 256 + k * 32 + cg * 8);
            acc[m] = __builtin_amdgcn_mfma_f32_16x16x32_bf16(afrag, bfrag, acc[m], 0, 0, 0);
        }
    }
    float* obase = out + (((size_t)bi * NF + 4) * C) * HW;
#pragma unroll
    for (int m = 0; m < 8; m++) {
#pragma unroll
        for (int r = 0; r < 4; r++) {
            int o = mh * 128 + m * 16 + cg * 4 + r;
            obase[(size_t)o * HW + p] = fmaxf(acc[m][r] + bias2[o], 0.f);
        }
    }
}

// ---------------- copy xm frames ----------------
__global__ __launch_bounds__(256) void copy_xm(const float* __restrict__ x, float* __restrict__ out) {
    int idx = blockIdx.x * 256 + threadIdx.x;   // 2 * 1048576 float4s
    int bi = idx >> 20;
    int i = idx & 1048575;
    size_t off = (size_t)bi * (NF * C * HW / 4) + i;
    ((f32x4*)out)[off] = ((const f32x4*)x)[off];
}

extern "C" void kernel_launch(void* const* d_in, const int* in_sizes, int n_in,
                              void* d_out, int out_size, void* d_ws, size_t ws_size,
                              hipStream_t stream) {
    const float* x    = (const float*)d_in[0];
    const float* qk_w = (const float*)d_in[2];
    const float* qv_w = (const float*)d_in[3];
    const float* mk_w = (const float*)d_in[4];
    const float* mv_w = (const float*)d_in[5];
    const float* sm_w = (const float*)d_in[6];
    const float* bns  = (const float*)d_in[7];
    const float* bnb  = (const float*)d_in[8];
    const float* bnm  = (const float*)d_in[9];
    const float* bnv  = (const float*)d_in[10];
    float* out = (float*)d_out;
    char* ws = (char*)d_ws;

    size_t off = 0;
    auto alloc = [&](size_t bytes) { size_t o = off; off += (bytes + 255) & ~(size_t)255; return o; };
    size_t WSF = alloc(256 * 256 * 2);
    size_t BIA = alloc(256 * 4);
    size_t WB  = alloc(2 * 160 * 256 * 2);
    size_t QKN = alloc((size_t)B * NQ * 32 * 2);
    size_t MKN = alloc((size_t)B * NK * 32 * 2);
    size_t MVT = alloc((size_t)B * CV * NK * 2);
    size_t UBU = alloc((size_t)B * HW * 256 * 2);
    size_t fixed = off;
    int kc = 4;
    size_t need4 = fixed + (size_t)B * 4 * NQ * 4 + (size_t)B * 4 * NQ * 128 * 4 + 1024;
    if (ws_size < need4) kc = 1;
    size_t LP = alloc((size_t)B * kc * NQ * 4);
    size_t OP = alloc((size_t)B * kc * NQ * 128 * 4);

    prep_k<<<577, 256, 0, stream>>>(qk_w, qv_w, mk_w, mv_w, sm_w, bns, bnb, bnm, bnv,
        (u16*)(ws + WSF), (float*)(ws + BIA), (u16*)(ws + WB));
    proj_mfma<<<640, 256, 0, stream>>>(x, (u16*)(ws + WB),
        (u16*)(ws + QKN), (u16*)(ws + MKN), (u16*)(ws + MVT), (u16*)(ws + UBU));
    attn_k<<<B * 32 * kc, 512, 0, stream>>>((u16*)(ws + QKN), (u16*)(ws + MKN),
        (u16*)(ws + MVT), (float*)(ws + OP), (float*)(ws + LP), kc);
    combine_k<<<256, 256, 0, stream>>>((float*)(ws + OP), (float*)(ws + LP),
        (u16*)(ws + UBU), kc);
    final_mfma<<<256, 256, 0, stream>>>((u16*)(ws + UBU), (u16*)(ws + WSF),
        (float*)(ws + BIA), out);
    copy_xm<<<8192, 256, 0, stream>>>(x, out);
}

// Round 3
// 148.965 us; speedup vs baseline: 3.4599x; 1.2609x over previous
//
#include <hip/hip_runtime.h>

typedef unsigned short u16;
typedef unsigned int u32;
typedef __attribute__((ext_vector_type(8))) short short8v;   // 8 bf16 (4 VGPRs)
typedef __attribute__((ext_vector_type(4))) float f32x4;
typedef __attribute__((ext_vector_type(16))) float f32x16;

#define B 2
#define NF 5
#define C 256
#define HW 4096
#define CV 128
#define NK 16384   // 4 frames * 4096
#define NQ 4096

__device__ __forceinline__ u16 f2bf(float f) {
    u32 u = __float_as_uint(f);
    u32 r = (u + 0x7FFFu + ((u >> 16) & 1u)) >> 16;   // RNE
    return (u16)r;
}

__device__ __forceinline__ u32 cvtpk(float lo, float hi) {
    u32 r;
    asm("v_cvt_pk_bf16_f32 %0, %1, %2" : "=v"(r) : "v"(lo), "v"(hi));
    return r;
}

// ---------------- prep: bf16 weight tables + BN folding ----------------
__global__ __launch_bounds__(256) void prep_k(
    const float* __restrict__ qk_w, const float* __restrict__ qv_w,
    const float* __restrict__ mk_w, const float* __restrict__ mv_w,
    const float* __restrict__ sm_w,
    const float* __restrict__ bns, const float* __restrict__ bnb,
    const float* __restrict__ bnm, const float* __restrict__ bnv,
    u16* __restrict__ wsf, float* __restrict__ bias2, u16* __restrict__ wb) {
    int bx = blockIdx.x, t = threadIdx.x;
    if (bx < 256) {
        int idx = bx * 256 + t;          // o*256 + c
        int o = idx >> 8;
        float inv = bns[o] / sqrtf(bnv[o] + 1e-5f);
        wsf[idx] = f2bf(sm_w[idx] * inv);
    } else if (bx < 576) {
        int j = (bx - 256) * 256 + t;    // < 81920
        int v = j / 40960, rr = j % 40960;
        int row = rr >> 8, c = rr & 255;
        float s;
        if (v == 0) s = (row < 32) ? mk_w[row * 256 + c] : mv_w[(row - 32) * 256 + c];
        else        s = (row < 32) ? qk_w[row * 256 + c] : qv_w[(row - 32) * 256 + c];
        wb[j] = f2bf(s);
    } else {
        int o = t;
        float inv = bns[o] / sqrtf(bnv[o] + 1e-5f);
        bias2[o] = bnb[o] - bnm[o] * inv;
    }
}

// ---------------- fused K+V projection via MFMA ----------------
__global__ __launch_bounds__(256) void proj_mfma(
    const float* __restrict__ x, const u16* __restrict__ wb,
    u16* __restrict__ qkn, u16* __restrict__ mkn,
    u16* __restrict__ mvt, u16* __restrict__ U) {
    int bx = blockIdx.x;        // 2*5*64 = 640
    int bi = bx / 320;
    int rem = bx % 320;
    int f = rem >> 6, pt = rem & 63;
    int t = threadIdx.x, w = t >> 6, lane = t & 63;
    int l15 = lane & 15, cg = lane >> 4;
    int p = pt * 64 + w * 16 + l15;
    const float* xp = x + (((size_t)bi * NF + f) * C) * HW + p;
    const u16* wrow = wb + (size_t)((f == 4) ? 160 : 0) * 256;

    f32x4 acc[10];
#pragma unroll
    for (int m = 0; m < 10; m++) acc[m] = (f32x4){0.f, 0.f, 0.f, 0.f};

    for (int k = 0; k < 8; k++) {
        float xv[8];
#pragma unroll
        for (int j = 0; j < 8; j++) xv[j] = xp[(size_t)(k * 32 + cg * 8 + j) * HW];
        short8v bfrag;
#pragma unroll
        for (int j = 0; j < 8; j++) bfrag[j] = (short)f2bf(xv[j]);
#pragma unroll
        for (int m = 0; m < 10; m++) {
            short8v afrag = *(const short8v*)(wrow + (size_t)(m * 16 + l15) * 256 + k * 32 + cg * 8);
            acc[m] = __builtin_amdgcn_mfma_f32_16x16x32_bf16(afrag, bfrag, acc[m], 0, 0, 0);
        }
    }

    float ssq = 0.f;
#pragma unroll
    for (int m = 0; m < 2; m++)
#pragma unroll
        for (int r = 0; r < 4; r++) ssq += acc[m][r] * acc[m][r];
    ssq += __shfl_xor(ssq, 16, 64);
    ssq += __shfl_xor(ssq, 32, 64);
    float rn = 1.0f / fmaxf(sqrtf(ssq), 1e-12f);

    if (f == 4) {
        u16* kd = qkn + ((size_t)bi * NQ + p) * 32;
#pragma unroll
        for (int m = 0; m < 2; m++)
#pragma unroll
            for (int r = 0; r < 4; r++) kd[m * 16 + cg * 4 + r] = f2bf(acc[m][r] * rn);
        u16* ud = U + ((size_t)bi * HW + p) * 256;
#pragma unroll
        for (int m = 2; m < 10; m++) {
            int vo = m * 16 - 32 + cg * 4;
            union { u16 h[4]; uint2 v; } pk;
#pragma unroll
            for (int r = 0; r < 4; r++) pk.h[r] = f2bf(acc[m][r]);
            *(uint2*)(ud + vo) = pk.v;
        }
    } else {
        u16* kd = mkn + ((size_t)bi * NK + f * HW + p) * 32;
#pragma unroll
        for (int m = 0; m < 2; m++)
#pragma unroll
            for (int r = 0; r < 4; r++) kd[m * 16 + cg * 4 + r] = f2bf(acc[m][r] * rn);
#pragma unroll
        for (int m = 2; m < 10; m++)
#pragma unroll
            for (int r = 0; r < 4; r++) {
                int vo = m * 16 - 32 + cg * 4 + r;
                mvt[((size_t)bi * CV + vo) * NK + f * HW + p] = f2bf(acc[m][r]);
            }
    }
}

// ---------------- flash attention v2: 32x32 MFMA, swapped QK^T, P in registers ----------------
// Per block: 4 waves, QBLK=128 (32 q/wave), KVBLK=64.
// S^T = mfma(A=K, B=Q): lane holds col q=l31, rows k=(reg&3)+8*(reg>>2)+4*hi (+t*32).
// PV:  O^T = mfma(A=V^T, B=P^T): B-frags built in-register via cvt_pk + shfl_xor(32).
__global__ __launch_bounds__(256) void attn_k(
    const u16* __restrict__ qkn, const u16* __restrict__ mkn,
    const u16* __restrict__ mvt, float* __restrict__ opart,
    float* __restrict__ lpart, int kc) {
    __shared__ alignas(16) u16 kl[64 * 32];    // [64 k][32 c], rows 64B, XOR-swizzled 16B slots
    __shared__ alignas(16) u16 vl[128 * 64];   // [128 v][64 k], rows 128B, XOR-swizzled

    int bx = blockIdx.x;
    int bi = bx / (32 * kc);
    int rem = bx % (32 * kc);
    int qt = rem / kc, kci = rem % kc;
    int chunk = NK / kc, iters = chunk / 64;
    int tid = threadIdx.x, w = tid >> 6, lane = tid & 63;
    int l31 = lane & 31, hi = lane >> 5;

    // Q B-frags (col q = l31, c = cc*16 + hi*8 + j), loaded once
    int qrow = qt * 128 + w * 32 + l31;
    const u16* qp = qkn + ((size_t)bi * NQ + qrow) * 32;
    short8v qf0 = *(const short8v*)(qp + hi * 8);
    short8v qf1 = *(const short8v*)(qp + 16 + hi * 8);

    f32x16 O[4];
#pragma unroll
    for (int n = 0; n < 4; n++)
#pragma unroll
        for (int i = 0; i < 16; i++) O[n][i] = 0.f;
    float lsum = 0.f;

    // staging: K = 256 chunks of 16B; V = 1024 chunks (4/thread)
    const u16* mknb = mkn + (size_t)bi * NK * 32;
    const u16* mvtb = mvt + (size_t)bi * CV * NK;
    int krow = tid >> 2, kcol = tid & 3;
    int klsoff = krow * 32 + ((kcol ^ (krow & 3)) * 8);
    int vrow[4], vcol[4], vlsoff[4];
#pragma unroll
    for (int r = 0; r < 4; r++) {
        int cidx = tid + 256 * r;
        vrow[r] = cidx >> 3; vcol[r] = cidx & 7;
        vlsoff[r] = vrow[r] * 64 + ((vcol[r] ^ (vrow[r] & 7)) * 8);
    }

    int k0 = kci * chunk;
    short8v kreg = *(const short8v*)(mknb + (size_t)(k0 + krow) * 32 + kcol * 8);
    short8v vreg[4];
#pragma unroll
    for (int r = 0; r < 4; r++)
        vreg[r] = *(const short8v*)(mvtb + (size_t)vrow[r] * NK + k0 + vcol[r] * 8);

    const float L2E = 1.44269504f;

    for (int it = 0; it < iters; ++it) {
        __syncthreads();   // previous tile's reads complete
        *(short8v*)(kl + klsoff) = kreg;
#pragma unroll
        for (int r = 0; r < 4; r++) *(short8v*)(vl + vlsoff[r]) = vreg[r];
        __syncthreads();   // tile ready
        if (it + 1 < iters) {   // prefetch next tile into regs (latency hidden by compute)
            int kn = k0 + 64;
            kreg = *(const short8v*)(mknb + (size_t)(kn + krow) * 32 + kcol * 8);
#pragma unroll
            for (int r = 0; r < 4; r++)
                vreg[r] = *(const short8v*)(mvtb + (size_t)vrow[r] * NK + kn + vcol[r] * 8);
        }
#pragma unroll
        for (int t = 0; t < 2; t++) {
            // S^T for k-subtile t (32 keys)
            int ar = t * 32 + l31;
            const u16* kb = kl + ar * 32;
            short8v ka0 = *(const short8v*)(kb + ((hi ^ (ar & 3)) * 8));
            short8v ka1 = *(const short8v*)(kb + (((2 + hi) ^ (ar & 3)) * 8));
            f32x16 st;
#pragma unroll
            for (int i = 0; i < 16; i++) st[i] = 0.f;
            st = __builtin_amdgcn_mfma_f32_32x32x16_bf16(ka0, qf0, st, 0, 0, 0);
            st = __builtin_amdgcn_mfma_f32_32x32x16_bf16(ka1, qf1, st, 0, 0, 0);
            // P = exp(s-1) (scores in [-1,1] => fixed-shift softmax is exact)
            float p[16];
#pragma unroll
            for (int i = 0; i < 16; i++) {
                p[i] = exp2f(fmaf(st[i], L2E, -L2E));
                lsum += p[i];
            }
            // pack pairs to bf16; exchange halves for B-frag assembly
            u32 c0[4], c1[4], x0[4], x1[4];
#pragma unroll
            for (int g = 0; g < 4; g++) {
                c0[g] = cvtpk(p[4 * g], p[4 * g + 1]);       // k = 8g+4hi+{0,1}
                c1[g] = cvtpk(p[4 * g + 2], p[4 * g + 3]);   // k = 8g+4hi+{2,3}
                x0[g] = (u32)__shfl_xor((int)c0[g], 32, 64);
                x1[g] = (u32)__shfl_xor((int)c1[g], 32, 64);
            }
#pragma unroll
            for (int half = 0; half < 2; half++) {
                int rgl = half * 2, rgh = rgl + 1;
                union { u32 wd[4]; short8v v; } bu;
                bu.wd[0] = hi ? x0[rgh] : c0[rgl];
                bu.wd[1] = hi ? x1[rgh] : c1[rgl];
                bu.wd[2] = hi ? c0[rgh] : x0[rgl];
                bu.wd[3] = hi ? c1[rgh] : x1[rgl];
                int kk = 2 * t + half;
#pragma unroll
                for (int n = 0; n < 4; n++) {
                    int vr = n * 32 + l31;
                    short8v va = *(const short8v*)(vl + vr * 64 + (((kk * 2 + hi) ^ (vr & 7)) * 8));
                    O[n] = __builtin_amdgcn_mfma_f32_32x32x16_bf16(va, bu.v, O[n], 0, 0, 0);
                }
            }
        }
        k0 += 64;
    }

    lsum += __shfl_xor(lsum, 32, 64);
    size_t pbase = (size_t)(bi * kc + kci) * 128;
#pragma unroll
    for (int n = 0; n < 4; n++)
#pragma unroll
        for (int reg = 0; reg < 16; reg++) {
            int v = n * 32 + (reg & 3) + 8 * (reg >> 2) + 4 * hi;
            opart[(pbase + v) * NQ + qrow] = O[n][reg];
        }
    if (hi == 0) lpart[(size_t)(bi * kc + kci) * NQ + qrow] = lsum;
}

// ---------------- split-K combine -> U[b][q][128..255] bf16 ----------------
// opart layout: [bi][kc][v=128][q=4096] f32 (coalesced along q)
__global__ __launch_bounds__(256) void combine_k(
    const float* __restrict__ opart, const float* __restrict__ lpart,
    u16* __restrict__ U, int kc) {
    int bx = blockIdx.x;              // B * 64 * 2 = 256
    int bi = bx >> 7;
    int qb = ((bx >> 1) & 63) << 6;
    int vh = bx & 1;
    int t = threadIdx.x;
    int q = qb + (t & 63);
    int v0 = vh * 64 + (t >> 6) * 16;
    float acc[16];
#pragma unroll
    for (int i = 0; i < 16; i++) acc[i] = 0.f;
    float lsum = 0.f;
    for (int k = 0; k < kc; k++) {
        const float* pp = opart + ((size_t)((bi * kc + k) * 128 + v0)) * NQ + q;
#pragma unroll
        for (int i = 0; i < 16; i++) acc[i] += pp[(size_t)i * NQ];
        lsum += lpart[(size_t)(bi * kc + k) * NQ + q];
    }
    float r = 1.0f / lsum;
    u16* ud = U + ((size_t)bi * HW + q) * 256 + 128 + v0;
    union { u16 h[8]; short8v v; } a, b;
#pragma unroll
    for (int e = 0; e < 8; e++) a.h[e] = f2bf(acc[e] * r);
#pragma unroll
    for (int e = 0; e < 8; e++) b.h[e] = f2bf(acc[8 + e] * r);
    *(short8v*)ud = a.v;
    *(short8v*)(ud + 8) = b.v;
}

// ---------------- output GEMM via MFMA (+folded BN+ReLU) ----------------
__global__ __launch_bounds__(256) void final_mfma(
    const u16* __restrict__ U, const u16* __restrict__ wsf,
    const float* __restrict__ bias2, float* __restrict__ out) {
    int bx = blockIdx.x;          // 2*2*64 = 256
    int bi = bx >> 7;
    int mh = (bx >> 6) & 1;
    int pt = bx & 63;
    int t = threadIdx.x, w = t >> 6, lane = t & 63;
    int l15 = lane & 15, cg = lane >> 4;
    int p = pt * 64 + w * 16 + l15;
    const u16* urow = U + ((size_t)bi * HW + p) * 256;
    const u16* wbase = wsf + (size_t)mh * 128 * 256;
    f32x4 acc[8];
#pragma unroll
    for (int m = 0; m < 8; m++) acc[m] = (f32x4){0.f, 0.f, 0.f, 0.f};
    for (int k = 0; k < 8; k++) {
        short8v bfrag = *(const short8v*)(urow + k * 32 + cg * 8);
#pragma unroll
        for (int m = 0; m < 8; m++) {
            short8v afrag = *(const short8v*)(wbase + (size_t)(m * 16 + l15) * 256 + k * 32 + cg * 8);
            acc[m] = __builtin_amdgcn_mfma_f32_16x16x32_bf16(afrag, bfrag, acc[m], 0, 0, 0);
        }
    }
    float* obase = out + (((size_t)bi * NF + 4) * C) * HW;
#pragma unroll
    for (int m = 0; m < 8; m++) {
#pragma unroll
        for (int r = 0; r < 4; r++) {
            int o = mh * 128 + m * 16 + cg * 4 + r;
            obase[(size_t)o * HW + p] = fmaxf(acc[m][r] + bias2[o], 0.f);
        }
    }
}

// ---------------- copy xm frames ----------------
__global__ __launch_bounds__(256) void copy_xm(const float* __restrict__ x, float* __restrict__ out) {
    int idx = blockIdx.x * 256 + threadIdx.x;   // 2 * 1048576 float4s
    int bi = idx >> 20;
    int i = idx & 1048575;
    size_t off = (size_t)bi * (NF * C * HW / 4) + i;
    ((f32x4*)out)[off] = ((const f32x4*)x)[off];
}

extern "C" void kernel_launch(void* const* d_in, const int* in_sizes, int n_in,
                              void* d_out, int out_size, void* d_ws, size_t ws_size,
                              hipStream_t stream) {
    const float* x    = (const float*)d_in[0];
    const float* qk_w = (const float*)d_in[2];
    const float* qv_w = (const float*)d_in[3];
    const float* mk_w = (const float*)d_in[4];
    const float* mv_w = (const float*)d_in[5];
    const float* sm_w = (const float*)d_in[6];
    const float* bns  = (const float*)d_in[7];
    const float* bnb  = (const float*)d_in[8];
    const float* bnm  = (const float*)d_in[9];
    const float* bnv  = (const float*)d_in[10];
    float* out = (float*)d_out;
    char* ws = (char*)d_ws;

    size_t off = 0;
    auto alloc = [&](size_t bytes) { size_t o = off; off += (bytes + 255) & ~(size_t)255; return o; };
    size_t WSF = alloc(256 * 256 * 2);
    size_t BIA = alloc(256 * 4);
    size_t WB  = alloc(2 * 160 * 256 * 2);
    size_t QKN = alloc((size_t)B * NQ * 32 * 2);
    size_t MKN = alloc((size_t)B * NK * 32 * 2);
    size_t MVT = alloc((size_t)B * CV * NK * 2);
    size_t UBU = alloc((size_t)B * HW * 256 * 2);
    size_t fixed = off;
    int kc = 8;
    {
        size_t need8 = fixed + (size_t)B * 8 * NQ * 4 + (size_t)B * 8 * (size_t)CV * NQ * 4 + 1024;
        size_t need4 = fixed + (size_t)B * 4 * NQ * 4 + (size_t)B * 4 * (size_t)CV * NQ * 4 + 1024;
        if (ws_size < need8) kc = (ws_size < need4) ? 1 : 4;
    }
    size_t LP = alloc((size_t)B * kc * NQ * 4);
    size_t OP = alloc((size_t)B * kc * (size_t)CV * NQ * 4);

    prep_k<<<577, 256, 0, stream>>>(qk_w, qv_w, mk_w, mv_w, sm_w, bns, bnb, bnm, bnv,
        (u16*)(ws + WSF), (float*)(ws + BIA), (u16*)(ws + WB));
    proj_mfma<<<640, 256, 0, stream>>>(x, (u16*)(ws + WB),
        (u16*)(ws + QKN), (u16*)(ws + MKN), (u16*)(ws + MVT), (u16*)(ws + UBU));
    attn_k<<<B * 32 * kc, 256, 0, stream>>>((u16*)(ws + QKN), (u16*)(ws + MKN),
        (u16*)(ws + MVT), (float*)(ws + OP), (float*)(ws + LP), kc);
    combine_k<<<256, 256, 0, stream>>>((float*)(ws + OP), (float*)(ws + LP),
        (u16*)(ws + UBU), kc);
    final_mfma<<<256, 256, 0, stream>>>((u16*)(ws + UBU), (u16*)(ws + WSF),
        (float*)(ws + BIA), out);
    copy_xm<<<8192, 256, 0, stream>>>(x, out);
}

// Round 4
// 142.258 us; speedup vs baseline: 3.6230x; 1.0471x over previous
//
#include <hip/hip_runtime.h>

typedef unsigned short u16;
typedef unsigned int u32;
typedef __attribute__((ext_vector_type(8))) short short8v;   // 8 bf16 (4 VGPRs)
typedef __attribute__((ext_vector_type(4))) float f32x4;
typedef __attribute__((ext_vector_type(16))) float f32x16;
typedef __attribute__((ext_vector_type(2))) int i32x2;

#define B 2
#define NF 5
#define C 256
#define HW 4096
#define CV 128
#define NK 16384   // 4 frames * 4096
#define NQ 4096

__device__ __forceinline__ u16 f2bf(float f) {
    u32 u = __float_as_uint(f);
    u32 r = (u + 0x7FFFu + ((u >> 16) & 1u)) >> 16;   // RNE
    return (u16)r;
}

__device__ __forceinline__ u32 cvtpk(float lo, float hi) {
    u32 r;
    asm("v_cvt_pk_bf16_f32 %0, %1, %2" : "=v"(r) : "v"(lo), "v"(hi));
    return r;
}

// vdst'[0:31]=src0[32:63]; src0'[32:63]=vdst[0:31]; other halves keep.
__device__ __forceinline__ i32x2 plswap(u32 vdst, u32 src0) {
    return __builtin_amdgcn_permlane32_swap((int)vdst, (int)src0, false, false);
}

// ---------------- prep: bf16 weight tables + BN folding ----------------
__global__ __launch_bounds__(256) void prep_k(
    const float* __restrict__ qk_w, const float* __restrict__ qv_w,
    const float* __restrict__ mk_w, const float* __restrict__ mv_w,
    const float* __restrict__ sm_w,
    const float* __restrict__ bns, const float* __restrict__ bnb,
    const float* __restrict__ bnm, const float* __restrict__ bnv,
    u16* __restrict__ wsf, float* __restrict__ bias2, u16* __restrict__ wb) {
    int bx = blockIdx.x, t = threadIdx.x;
    if (bx < 256) {
        int idx = bx * 256 + t;          // o*256 + c
        int o = idx >> 8;
        float inv = bns[o] / sqrtf(bnv[o] + 1e-5f);
        wsf[idx] = f2bf(sm_w[idx] * inv);
    } else if (bx < 576) {
        int j = (bx - 256) * 256 + t;    // < 81920
        int v = j / 40960, rr = j % 40960;
        int row = rr >> 8, c = rr & 255;
        float s;
        if (v == 0) s = (row < 32) ? mk_w[row * 256 + c] : mv_w[(row - 32) * 256 + c];
        else        s = (row < 32) ? qk_w[row * 256 + c] : qv_w[(row - 32) * 256 + c];
        wb[j] = f2bf(s);
    } else {
        int o = t;
        float inv = bns[o] / sqrtf(bnv[o] + 1e-5f);
        bias2[o] = bnb[o] - bnm[o] * inv;
    }
}

// ---------------- fused K+V projection via MFMA ----------------
// qkn is pre-scaled by log2(e): attn computes P = exp2(S_scaled) = e^S.
__global__ __launch_bounds__(256) void proj_mfma(
    const float* __restrict__ x, const u16* __restrict__ wb,
    u16* __restrict__ qkn, u16* __restrict__ mkn,
    u16* __restrict__ mvt, u16* __restrict__ U) {
    int bx = blockIdx.x;        // 2*5*64 = 640
    int bi = bx / 320;
    int rem = bx % 320;
    int f = rem >> 6, pt = rem & 63;
    int t = threadIdx.x, w = t >> 6, lane = t & 63;
    int l15 = lane & 15, cg = lane >> 4;
    int p = pt * 64 + w * 16 + l15;
    const float* xp = x + (((size_t)bi * NF + f) * C) * HW + p;
    const u16* wrow = wb + (size_t)((f == 4) ? 160 : 0) * 256;

    f32x4 acc[10];
#pragma unroll
    for (int m = 0; m < 10; m++) acc[m] = (f32x4){0.f, 0.f, 0.f, 0.f};

    for (int k = 0; k < 8; k++) {
        float xv[8];
#pragma unroll
        for (int j = 0; j < 8; j++) xv[j] = xp[(size_t)(k * 32 + cg * 8 + j) * HW];
        short8v bfrag;
#pragma unroll
        for (int j = 0; j < 8; j++) bfrag[j] = (short)f2bf(xv[j]);
#pragma unroll
        for (int m = 0; m < 10; m++) {
            short8v afrag = *(const short8v*)(wrow + (size_t)(m * 16 + l15) * 256 + k * 32 + cg * 8);
            acc[m] = __builtin_amdgcn_mfma_f32_16x16x32_bf16(afrag, bfrag, acc[m], 0, 0, 0);
        }
    }

    float ssq = 0.f;
#pragma unroll
    for (int m = 0; m < 2; m++)
#pragma unroll
        for (int r = 0; r < 4; r++) ssq += acc[m][r] * acc[m][r];
    ssq += __shfl_xor(ssq, 16, 64);
    ssq += __shfl_xor(ssq, 32, 64);
    float rn = 1.0f / fmaxf(sqrtf(ssq), 1e-12f);

    if (f == 4) {
        float rq = rn * 1.44269504f;   // fold log2(e) into Q
        u16* kd = qkn + ((size_t)bi * NQ + p) * 32;
#pragma unroll
        for (int m = 0; m < 2; m++)
#pragma unroll
            for (int r = 0; r < 4; r++) kd[m * 16 + cg * 4 + r] = f2bf(acc[m][r] * rq);
        u16* ud = U + ((size_t)bi * HW + p) * 256;
#pragma unroll
        for (int m = 2; m < 10; m++) {
            int vo = m * 16 - 32 + cg * 4;
            union { u16 h[4]; uint2 v; } pk;
#pragma unroll
            for (int r = 0; r < 4; r++) pk.h[r] = f2bf(acc[m][r]);
            *(uint2*)(ud + vo) = pk.v;
        }
    } else {
        u16* kd = mkn + ((size_t)bi * NK + f * HW + p) * 32;
#pragma unroll
        for (int m = 0; m < 2; m++)
#pragma unroll
            for (int r = 0; r < 4; r++) kd[m * 16 + cg * 4 + r] = f2bf(acc[m][r] * rn);
#pragma unroll
        for (int m = 2; m < 10; m++)
#pragma unroll
            for (int r = 0; r < 4; r++) {
                int vo = m * 16 - 32 + cg * 4 + r;
                mvt[((size_t)bi * CV + vo) * NK + f * HW + p] = f2bf(acc[m][r]);
            }
    }
}

// ---------------- flash attention v3: dbuf LDS, permlane32_swap P-assembly ----------------
__global__ __launch_bounds__(256) void attn_k(
    const u16* __restrict__ qkn, const u16* __restrict__ mkn,
    const u16* __restrict__ mvt, float* __restrict__ opart,
    float* __restrict__ lpart, int kc) {
    __shared__ alignas(16) u16 kl[2][64 * 32];    // [64 k][32 c], XOR-swizzled 16B slots
    __shared__ alignas(16) u16 vl[2][128 * 64];   // [128 v][64 k], XOR-swizzled

    int bx = blockIdx.x;
    int bi = bx / (32 * kc);
    int rem = bx % (32 * kc);
    int qt = rem / kc, kci = rem % kc;
    int chunk = NK / kc, iters = chunk / 64;
    int tid = threadIdx.x, w = tid >> 6, lane = tid & 63;
    int l31 = lane & 31, hi = lane >> 5;

    // Q B-frags (col q = l31), loaded once; pre-scaled by log2(e)
    int qrow = qt * 128 + w * 32 + l31;
    const u16* qp = qkn + ((size_t)bi * NQ + qrow) * 32;
    short8v qf0 = *(const short8v*)(qp + hi * 8);
    short8v qf1 = *(const short8v*)(qp + 16 + hi * 8);

    f32x16 O[4];
#pragma unroll
    for (int n = 0; n < 4; n++)
#pragma unroll
        for (int i = 0; i < 16; i++) O[n][i] = 0.f;
    float ls[4] = {0.f, 0.f, 0.f, 0.f};

    const u16* mknb = mkn + (size_t)bi * NK * 32;
    const u16* mvtb = mvt + (size_t)bi * CV * NK;
    int krow = tid >> 2, kcol = tid & 3;
    int klsoff = krow * 32 + ((kcol ^ (krow & 3)) * 8);
    int vrow[4], vcol[4], vlsoff[4];
#pragma unroll
    for (int r = 0; r < 4; r++) {
        int cidx = tid + 256 * r;
        vrow[r] = cidx >> 3; vcol[r] = cidx & 7;
        vlsoff[r] = vrow[r] * 64 + ((vcol[r] ^ (vrow[r] & 7)) * 8);
    }

    int k0 = kci * chunk;
    short8v kreg = *(const short8v*)(mknb + (size_t)(k0 + krow) * 32 + kcol * 8);
    short8v vreg[4];
#pragma unroll
    for (int r = 0; r < 4; r++)
        vreg[r] = *(const short8v*)(mvtb + (size_t)vrow[r] * NK + k0 + vcol[r] * 8);

    int c = 0;
    for (int it = 0; it < iters; ++it) {
        // stage current tile into buf c (safe: buf c last read two iters ago, one barrier since)
        *(short8v*)(&kl[c][0] + klsoff) = kreg;
#pragma unroll
        for (int r = 0; r < 4; r++) *(short8v*)(&vl[c][0] + vlsoff[r]) = vreg[r];
        if (it + 1 < iters) {   // prefetch next tile into regs (full iter of latency)
            int kn = k0 + 64;
            kreg = *(const short8v*)(mknb + (size_t)(kn + krow) * 32 + kcol * 8);
#pragma unroll
            for (int r = 0; r < 4; r++)
                vreg[r] = *(const short8v*)(mvtb + (size_t)vrow[r] * NK + kn + vcol[r] * 8);
        }
        __syncthreads();
        const u16* klr = &kl[c][0];
        const u16* vlr = &vl[c][0];
#pragma unroll
        for (int t = 0; t < 2; t++) {
            int ar = t * 32 + l31;
            const u16* kb = klr + ar * 32;
            short8v ka0 = *(const short8v*)(kb + ((hi ^ (ar & 3)) * 8));
            short8v ka1 = *(const short8v*)(kb + (((2 + hi) ^ (ar & 3)) * 8));
            f32x16 st;
#pragma unroll
            for (int i = 0; i < 16; i++) st[i] = 0.f;
            st = __builtin_amdgcn_mfma_f32_32x32x16_bf16(ka0, qf0, st, 0, 0, 0);
            st = __builtin_amdgcn_mfma_f32_32x32x16_bf16(ka1, qf1, st, 0, 0, 0);
            // P = e^s  (Q pre-scaled by log2e; scores bounded => no max tracking)
            float p[16];
#pragma unroll
            for (int i = 0; i < 16; i++) p[i] = exp2f(st[i]);
#pragma unroll
            for (int g = 0; g < 4; g++)
                ls[g] += ((p[4 * g] + p[4 * g + 1]) + (p[4 * g + 2] + p[4 * g + 3]));
            u32 c0[4], c1[4];
#pragma unroll
            for (int g = 0; g < 4; g++) {
                c0[g] = cvtpk(p[4 * g], p[4 * g + 1]);       // keys 8g+4hi+{0,1}
                c1[g] = cvtpk(p[4 * g + 2], p[4 * g + 3]);   // keys 8g+4hi+{2,3}
            }
#pragma unroll
            for (int half = 0; half < 2; half++) {
                i32x2 s0 = plswap(c0[2 * half + 1], c0[2 * half]);
                i32x2 s1 = plswap(c1[2 * half + 1], c1[2 * half]);
                union { u32 wd[4]; short8v v; } bu;
                bu.wd[0] = (u32)s0[1];
                bu.wd[1] = (u32)s1[1];
                bu.wd[2] = (u32)s0[0];
                bu.wd[3] = (u32)s1[0];
                int kk = 2 * t + half;
#pragma unroll
                for (int n = 0; n < 4; n++) {
                    int vr = n * 32 + l31;
                    short8v va = *(const short8v*)(vlr + vr * 64 + (((kk * 2 + hi) ^ (vr & 7)) * 8));
                    O[n] = __builtin_amdgcn_mfma_f32_32x32x16_bf16(va, bu.v, O[n], 0, 0, 0);
                }
            }
        }
        c ^= 1;
        k0 += 64;
    }

    float lsum = (ls[0] + ls[1]) + (ls[2] + ls[3]);
    lsum += __shfl_xor(lsum, 32, 64);
    size_t pbase = (size_t)(bi * kc + kci) * 128;
#pragma unroll
    for (int n = 0; n < 4; n++)
#pragma unroll
        for (int reg = 0; reg < 16; reg++) {
            int v = n * 32 + (reg & 3) + 8 * (reg >> 2) + 4 * hi;
            opart[(pbase + v) * NQ + qrow] = O[n][reg];
        }
    if (hi == 0) lpart[(size_t)(bi * kc + kci) * NQ + qrow] = lsum;
}

// ---------------- split-K combine -> U[b][q][128..255] bf16 ----------------
__global__ __launch_bounds__(256) void combine_k(
    const float* __restrict__ opart, const float* __restrict__ lpart,
    u16* __restrict__ U, int kc) {
    int bx = blockIdx.x;              // B * 64 * 2 = 256
    int bi = bx >> 7;
    int qb = ((bx >> 1) & 63) << 6;
    int vh = bx & 1;
    int t = threadIdx.x;
    int q = qb + (t & 63);
    int v0 = vh * 64 + (t >> 6) * 16;
    float acc[16];
#pragma unroll
    for (int i = 0; i < 16; i++) acc[i] = 0.f;
    float lsum = 0.f;
    for (int k = 0; k < kc; k++) {
        const float* pp = opart + ((size_t)((bi * kc + k) * 128 + v0)) * NQ + q;
#pragma unroll
        for (int i = 0; i < 16; i++) acc[i] += pp[(size_t)i * NQ];
        lsum += lpart[(size_t)(bi * kc + k) * NQ + q];
    }
    float r = 1.0f / lsum;
    u16* ud = U + ((size_t)bi * HW + q) * 256 + 128 + v0;
    union { u16 h[8]; short8v v; } a, b;
#pragma unroll
    for (int e = 0; e < 8; e++) a.h[e] = f2bf(acc[e] * r);
#pragma unroll
    for (int e = 0; e < 8; e++) b.h[e] = f2bf(acc[8 + e] * r);
    *(short8v*)ud = a.v;
    *(short8v*)(ud + 8) = b.v;
}

// ---------------- output GEMM via MFMA (+folded BN+ReLU) ----------------
__global__ __launch_bounds__(256) void final_mfma(
    const u16* __restrict__ U, const u16* __restrict__ wsf,
    const float* __restrict__ bias2, float* __restrict__ out) {
    int bx = blockIdx.x;          // 2*2*64 = 256
    int bi = bx >> 7;
    int mh = (bx >> 6) & 1;
    int pt = bx & 63;
    int t = threadIdx.x, w = t >> 6, lane = t & 63;
    int l15 = lane & 15, cg = lane >> 4;
    int p = pt * 64 + w * 16 + l15;
    const u16* urow = U + ((size_t)bi * HW + p) * 256;
    const u16* wbase = wsf + (size_t)mh * 128 * 256;
    f32x4 acc[8];
#pragma unroll
    for (int m = 0; m < 8; m++) acc[m] = (f32x4){0.f, 0.f, 0.f, 0.f};
    for (int k = 0; k < 8; k++) {
        short8v bfrag = *(const short8v*)(urow + k * 32 + cg * 8);
#pragma unroll
        for (int m = 0; m < 8; m++) {
            short8v afrag = *(const short8v*)(wbase + (size_t)(m * 16 + l15) * 256 + k * 32 + cg * 8);
            acc[m] = __builtin_amdgcn_mfma_f32_16x16x32_bf16(afrag, bfrag, acc[m], 0, 0, 0);
        }
    }
    float* obase = out + (((size_t)bi * NF + 4) * C) * HW;
#pragma unroll
    for (int m = 0; m < 8; m++) {
#pragma unroll
        for (int r = 0; r < 4; r++) {
            int o = mh * 128 + m * 16 + cg * 4 + r;
            obase[(size_t)o * HW + p] = fmaxf(acc[m][r] + bias2[o], 0.f);
        }
    }
}

// ---------------- copy xm frames ----------------
__global__ __launch_bounds__(256) void copy_xm(const float* __restrict__ x, float* __restrict__ out) {
    int idx = blockIdx.x * 256 + threadIdx.x;   // 2 * 1048576 float4s
    int bi = idx >> 20;
    int i = idx & 1048575;
    size_t off = (size_t)bi * (NF * C * HW / 4) + i;
    ((f32x4*)out)[off] = ((const f32x4*)x)[off];
}

extern "C" void kernel_launch(void* const* d_in, const int* in_sizes, int n_in,
                              void* d_out, int out_size, void* d_ws, size_t ws_size,
                              hipStream_t stream) {
    const float* x    = (const float*)d_in[0];
    const float* qk_w = (const float*)d_in[2];
    const float* qv_w = (const float*)d_in[3];
    const float* mk_w = (const float*)d_in[4];
    const float* mv_w = (const float*)d_in[5];
    const float* sm_w = (const float*)d_in[6];
    const float* bns  = (const float*)d_in[7];
    const float* bnb  = (const float*)d_in[8];
    const float* bnm  = (const float*)d_in[9];
    const float* bnv  = (const float*)d_in[10];
    float* out = (float*)d_out;
    char* ws = (char*)d_ws;

    size_t off = 0;
    auto alloc = [&](size_t bytes) { size_t o = off; off += (bytes + 255) & ~(size_t)255; return o; };
    size_t WSF = alloc(256 * 256 * 2);
    size_t BIA = alloc(256 * 4);
    size_t WB  = alloc(2 * 160 * 256 * 2);
    size_t QKN = alloc((size_t)B * NQ * 32 * 2);
    size_t MKN = alloc((size_t)B * NK * 32 * 2);
    size_t MVT = alloc((size_t)B * CV * NK * 2);
    size_t UBU = alloc((size_t)B * HW * 256 * 2);
    size_t fixed = off;
    int kc = 8;
    {
        size_t need8 = fixed + (size_t)B * 8 * NQ * 4 + (size_t)B * 8 * (size_t)CV * NQ * 4 + 1024;
        size_t need4 = fixed + (size_t)B * 4 * NQ * 4 + (size_t)B * 4 * (size_t)CV * NQ * 4 + 1024;
        if (ws_size < need8) kc = (ws_size < need4) ? 1 : 4;
    }
    size_t LP = alloc((size_t)B * kc * NQ * 4);
    size_t OP = alloc((size_t)B * kc * (size_t)CV * NQ * 4);

    prep_k<<<577, 256, 0, stream>>>(qk_w, qv_w, mk_w, mv_w, sm_w, bns, bnb, bnm, bnv,
        (u16*)(ws + WSF), (float*)(ws + BIA), (u16*)(ws + WB));
    proj_mfma<<<640, 256, 0, stream>>>(x, (u16*)(ws + WB),
        (u16*)(ws + QKN), (u16*)(ws + MKN), (u16*)(ws + MVT), (u16*)(ws + UBU));
    attn_k<<<B * 32 * kc, 256, 0, stream>>>((u16*)(ws + QKN), (u16*)(ws + MKN),
        (u16*)(ws + MVT), (float*)(ws + OP), (float*)(ws + LP), kc);
    combine_k<<<256, 256, 0, stream>>>((float*)(ws + OP), (float*)(ws + LP),
        (u16*)(ws + UBU), kc);
    final_mfma<<<256, 256, 0, stream>>>((u16*)(ws + UBU), (u16*)(ws + WSF),
        (float*)(ws + BIA), out);
    copy_xm<<<8192, 256, 0, stream>>>(x, out);
}